// Round 4
// baseline (741.443 us; speedup 1.0000x reference)
//
#include <hip/hip_runtime.h>
#include <hip/hip_bf16.h>
#include <cstdint>

// Fused: ConvTranspose2d(128->256, k=4, s=2, p=1) + MaxPool2 + Hardtanh + mean + tanh
// B=64, Cin=128, Cout=256, H=W=64. Output [64,256,1,1] fp32.
//
// R4: 256-thr blocks (4 waves), 2 pooled rows x 128 couts per block.
// x tile packed [4][64][128] bf16 = 64 KB LDS (XOR-swizzled, VGPR halo masks).
// Weights NOT staged in LDS: loaded per-tap from global (1 MB wT, L2-resident)
// straight into VGPRs -> barrier-free main loop, half the LDS traffic.
// __launch_bounds__(256,2): caps VGPR at 256 under BOTH known semantics
// (2 blocks/CU x 1 wave/SIMD, or 2 waves/EU) -> 2 blocks/CU, 2 waves/SIMD.
// (R2/R3 lesson: (512,2) means 2 *blocks* -> 128-VGPR cap -> 850 MB spill.)

typedef __attribute__((ext_vector_type(8))) short short8;
typedef __attribute__((ext_vector_type(4))) float f32x4;

__device__ __forceinline__ void async16(const void* g, void* l) {
  __builtin_amdgcn_global_load_lds(
      reinterpret_cast<const unsigned int __attribute__((address_space(1)))*>(
          reinterpret_cast<uintptr_t>(g)),
      reinterpret_cast<unsigned int __attribute__((address_space(3)))*>(
          reinterpret_cast<uintptr_t>(l)),
      16, 0, 0);
}

__device__ __forceinline__ unsigned short f2bf(float f) {
  union { float f; unsigned int u; } v; v.f = f;
  unsigned int u = v.u;
  return (unsigned short)((u + 0x7fffu + ((u >> 16) & 1u)) >> 16);
}

__device__ __forceinline__ short8 and_mask(short8 v, unsigned m) {
  union { short8 s; unsigned u[4]; } x;
  x.s = v;
  x.u[0] &= m; x.u[1] &= m; x.u[2] &= m; x.u[3] &= m;
  return x.s;
}

// ---------------- Pass A: x NCHW f32 -> NHWC bf16 ----------------
__global__ __launch_bounds__(256) void k_xpose(const float* __restrict__ x,
                                               unsigned short* __restrict__ xT) {
  __shared__ float tile[64][132];
  int bid = blockIdx.x;
  int b = bid >> 6, h = bid & 63;
  const float* src = x + (size_t)b * 524288 + h * 64;
  int w = threadIdx.x & 63, cg = threadIdx.x >> 6;
#pragma unroll
  for (int cc = 0; cc < 32; ++cc) {
    int cin = cc * 4 + cg;
    tile[w][cin] = src[(size_t)cin * 4096 + w];
  }
  __syncthreads();
  unsigned short* dst = xT + (size_t)(b * 64 + h) * 8192;
#pragma unroll
  for (int it = 0; it < 4; ++it) {
    int e = it * 2048 + threadIdx.x * 8;
    int ww = e >> 7, cin = e & 127;
    unsigned int pk[4];
#pragma unroll
    for (int j = 0; j < 4; ++j) {
      unsigned int lo = f2bf(tile[ww][cin + 2 * j]);
      unsigned int hi = f2bf(tile[ww][cin + 2 * j + 1]);
      pk[j] = lo | (hi << 16);
    }
    *reinterpret_cast<uint4*>(dst + e) = make_uint4(pk[0], pk[1], pk[2], pk[3]);
  }
}

// ---------------- Pass B: w [cin][cout][kh][kw] f32 -> wT [kh*4+kw][cout][cin] bf16 ----
__global__ __launch_bounds__(256) void k_wpack(const float* __restrict__ w,
                                               unsigned short* __restrict__ wT) {
  int o = blockIdx.x * 256 + threadIdx.x;
  int cin = o & 127;
  int cout = (o >> 7) & 255;
  int khkw = o >> 15;
  int kh = khkw >> 2, kw = khkw & 3;
  float f = w[((size_t)cin * 256 + cout) * 16 + kh * 4 + kw];
  wT[o] = f2bf(f);
}

// ---------------- Main fused kernel ----------------
// LDS: x tile [4 rows][64 cols][128 cin] bf16 = 65536 B. No weight LDS.
#define LDS_TOTAL 65536

__global__ __launch_bounds__(256, 2) void k_main(
    const unsigned short* __restrict__ xT,
    const unsigned short* __restrict__ wT,
    const float* __restrict__ bias,
    float* __restrict__ acc) {
  extern __shared__ char smem[];
  const int bid = blockIdx.x;
  const int pr  = bid & 31;         // pooled rows 2pr, 2pr+1
  const int nt  = (bid >> 5) & 1;   // cout half (consecutive bids share nt -> L1/L2 reuse)
  const int b   = bid >> 6;
  const int n0  = nt * 128;
  const int tid  = threadIdx.x;
  const int lane = tid & 63;
  const int wid  = tid >> 6;   // 0..3
  const int wm   = wid >> 1;   // pooled row 2pr+wm
  const int wn   = wid & 1;    // cout 64-half
  const int l15  = lane & 15;
  const int l4   = lane >> 4;

  // ---- stage x tile [4][64][128]: tile row r <- input row 2pr-1+r ----
  {
    const char* xTb = (const char*)xT + (size_t)b * 1048576;  // 64 rows * 16384 B
#pragma unroll
    for (int it = 0; it < 16; ++it) {
      const int gbase = it * 4096 + wid * 1024;   // wave-uniform chunk (within one row)
      const int g = gbase + lane * 16;
      const int r = g >> 14;                      // 0..3, wave-uniform per chunk
      const int ir = 2 * pr - 1 + r;
      if ((unsigned)ir < 64u) {
        const int rc = g >> 8;                    // row*64+col index
        const int key = (rc & 7) << 4;
        const char* src = xTb + ir * 16384 + (rc & 63) * 256 + ((g & 255) ^ key);
        async16(src, smem + gbase);               // HW adds lane*16 (linear dest)
      } else {
        *reinterpret_cast<f32x4*>(smem + g) = (f32x4){0.f, 0.f, 0.f, 0.f};
      }
    }
  }
  __syncthreads();   // the ONLY barrier: x tile read-only from here on

  const int KHt[2][2] = {{1, 3}, {2, 0}};
  const int DHt[2][2] = {{0, -1}, {0, 1}};
  const unsigned kmneg = (l15 == 0)  ? 0u : ~0u;  // kill col -1 lane
  const unsigned kmpos = (l15 == 15) ? 0u : ~0u;  // kill col 64 lane

  f32x4 accf[4][4], rm[4][4];
#pragma unroll
  for (int mi = 0; mi < 4; ++mi)
#pragma unroll
    for (int ni = 0; ni < 4; ++ni) accf[mi][ni] = (f32x4){0.f, 0.f, 0.f, 0.f};

  // B global addressing: wT[khkw][cout][cin] bf16; this lane reads
  // cout = n0 + wn*64 + ni*16 + l15, cin = kk*32 + l4*8  (16B per load)
  const char* wb0 = (const char*)wT + (size_t)n0 * 256;
  const int boff = (wn * 64 + l15) * 256 + l4 * 16;   // + ni*4096 + kk*64

#pragma unroll
  for (int q = 0; q < 4; ++q) {
    const int qh = q >> 1, qw = q & 1;
#pragma unroll
    for (int t = 0; t < 4; ++t) {
      const int th = t >> 1, tw = t & 1;
      const int kh = KHt[qh][th], kw = KHt[qw][tw];
      const char* wb = wb0 + (kh * 4 + kw) * 65536;
      // load all 16 B-fragments for this tap into VGPRs (L2-resident)
      short8 bb[4][4];
#pragma unroll
      for (int ni = 0; ni < 4; ++ni)
#pragma unroll
        for (int kk = 0; kk < 4; ++kk)
          bb[ni][kk] = *reinterpret_cast<const short8*>(wb + boff + ni * 4096 + kk * 64);

      const int dr = DHt[qh][th];
      const int dw = DHt[qw][tw];
      const int ar = wm + 1 + dr;           // x tile row (0..3)
      int aoff[4], akey[4];
#pragma unroll
      for (int mi = 0; mi < 4; ++mi) {
        int col = mi * 16 + l15 + dw;
        int colc = col < 0 ? 0 : (col > 63 ? 63 : col);
        int rc = ar * 64 + colc;
        aoff[mi] = rc * 256 + l4 * 16;
        akey[mi] = (rc & 7) << 4;
      }
#pragma unroll
      for (int kk = 0; kk < 4; ++kk) {
        short8 a[4];
#pragma unroll
        for (int mi = 0; mi < 4; ++mi)
          a[mi] = *reinterpret_cast<const short8*>(smem + ((aoff[mi] + kk * 64) ^ akey[mi]));
        if (dw < 0) a[0] = and_mask(a[0], kmneg);
        if (dw > 0) a[3] = and_mask(a[3], kmpos);
#pragma unroll
        for (int mi = 0; mi < 4; ++mi)
#pragma unroll
          for (int ni = 0; ni < 4; ++ni)
            accf[mi][ni] = __builtin_amdgcn_mfma_f32_16x16x32_bf16(a[mi], bb[ni][kk], accf[mi][ni], 0, 0, 0);
      }
      if (t == 3) {  // parity finished: fold into running max, reset acc
#pragma unroll
        for (int mi = 0; mi < 4; ++mi)
#pragma unroll
          for (int ni = 0; ni < 4; ++ni) {
            if (q == 0) {
              rm[mi][ni] = accf[mi][ni];
            } else {
#pragma unroll
              for (int rr = 0; rr < 4; ++rr)
                rm[mi][ni][rr] = fmaxf(rm[mi][ni][rr], accf[mi][ni][rr]);
            }
            accf[mi][ni] = (f32x4){0.f, 0.f, 0.f, 0.f};
          }
      }
    }
  }

  // ---- epilogue: +bias, clamp, sum pixels, wave-reduce, atomicAdd ----
#pragma unroll
  for (int ni = 0; ni < 4; ++ni) {
    const int cout = n0 + wn * 64 + ni * 16 + l15;
    const float bv = bias[cout];
    float s = 0.f;
#pragma unroll
    for (int mi = 0; mi < 4; ++mi)
#pragma unroll
      for (int rr = 0; rr < 4; ++rr) {
        float v = rm[mi][ni][rr] + bv;
        v = fminf(1.f, fmaxf(-1.f, v));
        s += v;
      }
    s += __shfl_xor(s, 16, 64);
    s += __shfl_xor(s, 32, 64);
    if (lane < 16) atomicAdd(&acc[b * 256 + cout], s);
  }
}

// ---------------- finalize ----------------
__global__ __launch_bounds__(256) void k_fin(const float* __restrict__ acc,
                                             float* __restrict__ out) {
  int i = blockIdx.x * 256 + threadIdx.x;
  out[i] = tanhf(acc[i] * (1.0f / 4096.0f));
}

extern "C" void kernel_launch(void* const* d_in, const int* in_sizes, int n_in,
                              void* d_out, int out_size, void* d_ws, size_t ws_size,
                              hipStream_t stream) {
  const float* x    = (const float*)d_in[0];
  const float* w    = (const float*)d_in[1];
  const float* bias = (const float*)d_in[2];
  float* out = (float*)d_out;
  char* ws = (char*)d_ws;

  float* acc          = (float*)ws;                                // 65536 B
  unsigned short* xT  = (unsigned short*)(ws + 65536);             // 67108864 B
  unsigned short* wT  = (unsigned short*)(ws + 65536 + 67108864);  // 1048576 B

  hipMemsetAsync(acc, 0, 65536, stream);
  k_xpose<<<4096, 256, 0, stream>>>(x, xT);
  k_wpack<<<2048, 256, 0, stream>>>(w, wT);

  hipFuncSetAttribute(reinterpret_cast<const void*>(k_main),
                      hipFuncAttributeMaxDynamicSharedMemorySize, LDS_TOTAL);
  k_main<<<4096, 256, LDS_TOTAL, stream>>>(xT, wT, bias, acc);
  k_fin<<<64, 256, 0, stream>>>(acc, out);
}